// Round 7
// baseline (115.135 us; speedup 1.0000x reference)
//
#include <hip/hip_runtime.h>
#include <hip/hip_bf16.h>

#define NB 8
#define CC 256
#define OO 768
#define LL 512
#define VV 25
#define PP 3
#define KM 768
#define NKC 24          // K-chunks of 32
#define LT 2            // l's per block

typedef __attribute__((ext_vector_type(8))) short short8v;
typedef __attribute__((ext_vector_type(4))) float float4v;
typedef __attribute__((ext_vector_type(4))) int int4v;

__device__ inline unsigned pk2(float a, float b){
    __hip_bfloat16 ha = __float2bfloat16(a), hb = __float2bfloat16(b);
    unsigned short ua = *(unsigned short*)&ha, ub = *(unsigned short*)&hb;
    return (unsigned)ua | ((unsigned)ub << 16);
}

// ---------------------------------------------------------------------------
// W -> fragment-ordered bf16 layout in d_ws (unchanged from round 6):
//   idx = (((kc*4 + wm)*4 + mt)*64 + lane)*8 + j
//   holds W'[c][k], c = wm*64+mt*16+(lane&15), k = kc*32+(lane>>4)*8+j
//   W'[c][k] = W[(p*256+c)*256 + ci], k = cib*192+p*64+ci6, ci = cib*64+ci6.
// ---------------------------------------------------------------------------
__global__ __launch_bounds__(256) void wperm_kernel(const float* __restrict__ W,
                                                    __hip_bfloat16* __restrict__ Wp) {
    int idx = blockIdx.x * 256 + threadIdx.x;
    if (idx >= OO * CC) return;
    int j    = idx & 7;
    int lane = (idx >> 3) & 63;
    int mt   = (idx >> 9) & 3;
    int wm   = (idx >> 11) & 3;
    int kc   = idx >> 13;                    // 0..23
    int c = wm * 64 + mt * 16 + (lane & 15);
    int k = kc * 32 + ((lane >> 4) << 3) + j;
    int cib = k / 192;
    int r = k - cib * 192;
    int p = r >> 6;
    int ci = cib * 64 + (r & 63);
    Wp[idx] = __float2bfloat16(W[(p * 256 + c) * 256 + ci]);
}

// ---------------------------------------------------------------------------
// Fused: window-sum + Z-gen(1-ahead, dbuf) + K=768 MFMA GEMM + BN/relu/res.
// Block = (n, 2 l's), 256 threads / 4 waves, 24 KB LDS -> many blocks/CU.
// W-fragments direct from global (L2-resident) with register rotation.
// ---------------------------------------------------------------------------
__global__ __launch_bounds__(256, 4) void fused_main_kernel(
    const float* __restrict__ x,
    const __hip_bfloat16* __restrict__ Wp,
    const float* __restrict__ A,
    const float* __restrict__ gamma, const float* __restrict__ beta,
    const float* __restrict__ mean, const float* __restrict__ var,
    float* __restrict__ out)
{
    __shared__ __hip_bfloat16 Zb[2][64 * 32];    // Z^T dbuf (8 KB)
    __shared__ __hip_bfloat16 xsh[128 * 32];     // ws-x [ci6*2+l][v pad32] (8 KB)
    __shared__ __hip_bfloat16 a2t[3 * 32 * 32];  // A^T [p*32+w][v pad32] (6 KB)
    __shared__ float scsh[512];                  // 2 KB

    const int tid  = threadIdx.x;
    const int lane = tid & 63, wid = tid >> 6;
    const int lcol = lane & 15, grp = lane >> 4;
    const int bid0 = blockIdx.x;
    const int swz = (bid0 & 7) * 256 + (bid0 >> 3);   // XCD-contiguous chunks
    const int n  = swz >> 8;
    const int l0 = (swz & 255) * LT;
    const int wm = wid;                       // main-GEMM: wave owns 64 c's
    const int mt_z = wid & 1, l_z = wid >> 1; // zgen roles

    // ---- prologue: zero pads, BN coefs ----
    {
        int4v z = {0, 0, 0, 0};
        ((int4v*)xsh)[tid] = z;
        ((int4v*)xsh)[tid + 256] = z;
        ((int4v*)a2t)[tid] = z;
        if (tid < 128) ((int4v*)a2t)[tid + 256] = z;
        float sc = gamma[tid] * rsqrtf(var[tid] + 1e-5f);
        scsh[tid] = sc;
        scsh[256 + tid] = beta[tid] - mean[tid] * sc;
    }
    __syncthreads();
    // A^T scatter: a2t[p*32 + w][v ^ swz]
    for (int idx = tid; idx < PP * VV * VV; idx += 256) {
        int p = idx / 625, r = idx - p * 625, v = r / 25, w = r - v * 25;
        int R = p * 32 + w;
        int e = (((v >> 3) ^ ((R >> 1) & 3)) << 3) | (v & 7);
        a2t[R * 32 + e] = __float2bfloat16(A[idx]);
    }

    auto stage_xs = [&](int cib) {
        for (int cc = tid; cc < 1600; cc += 256) {
            int ci6 = cc / 25, v = cc - ci6 * 25;
            const float* xp = x + ((size_t)(n * CC + cib * 64 + ci6) * LL) * VV + v;
            float rbuf[10];
            #pragma unroll
            for (int j = 0; j < 10; ++j) {
                int lj = l0 - 8 + j;
                rbuf[j] = (lj >= 0) ? xp[(size_t)lj * VV] : 0.f;
            }
            float wsv = 0.f;
            #pragma unroll
            for (int j = 0; j < 9; ++j) wsv += rbuf[j];
            #pragma unroll
            for (int i = 0; i < LT; ++i) {
                int R = ci6 * LT + i;
                int e = (((v >> 3) ^ ((R >> 1) & 3)) << 3) | (v & 7);
                xsh[R * 32 + e] = __float2bfloat16(wsv);
                if (i < LT - 1) wsv += rbuf[9 + i] - rbuf[i];
            }
        }
    };
    auto zgen = [&](int kc, int zbuf) {
        int p = (kc % 6) >> 1, h = kc & 1;
        int ci6 = h * 32 + mt_z * 16 + lcol;
        int R = ci6 * LT + l_z;
        short8v az = *(const short8v*)&xsh[R * 32 + ((grp ^ ((R >> 1) & 3)) << 3)];
        #pragma unroll
        for (int wt = 0; wt < 2; ++wt) {
            int R2 = p * 32 + wt * 16 + lcol;
            short8v bz = *(const short8v*)&a2t[R2 * 32 + ((grp ^ ((R2 >> 1) & 3)) << 3)];
            float4v zc = {0.f, 0.f, 0.f, 0.f};
            zc = __builtin_amdgcn_mfma_f32_16x16x32_bf16(az, bz, zc, 0, 0, 0);
            int R3 = l_z * 32 + wt * 16 + lcol;
            int eb = (mt_z * 2 + (grp >> 1)) ^ ((R3 >> 1) & 3);
            unsigned* dst = (unsigned*)&Zb[zbuf][R3 * 32 + (eb << 3) + ((grp & 1) << 2)];
            dst[0] = pk2(zc[0], zc[1]);
            dst[1] = pk2(zc[2], zc[3]);
        }
    };

    float4v acc[4][4];
    #pragma unroll
    for (int i = 0; i < 4; ++i)
        #pragma unroll
        for (int j = 0; j < 4; ++j) acc[i][j] = (float4v){0.f, 0.f, 0.f, 0.f};

    const __hip_bfloat16* afbase = Wp + ((size_t)(wm * 4) * 64 + lane) * 8;

#define KSTEP(kc, j, afc, afn) do {                                           \
    if ((kc) + 1 < NKC) {                                                     \
        const __hip_bfloat16* ap_ = afbase + (size_t)((kc) + 1) * 8192;       \
        _Pragma("unroll")                                                     \
        for (int mt_ = 0; mt_ < 4; ++mt_)                                     \
            afn[mt_] = *(const short8v*)(ap_ + mt_ * 512);                    \
    }                                                                         \
    if ((j) < 5) zgen((kc) + 1, ((kc) + 1) & 1);                              \
    {                                                                         \
        const __hip_bfloat16* zcur_ = &Zb[(kc) & 1][0];                       \
        short8v bf_[4];                                                       \
        _Pragma("unroll")                                                     \
        for (int nt_ = 0; nt_ < 4; ++nt_) {                                   \
            int R3_ = nt_ * 16 + lcol;                                        \
            bf_[nt_] = *(const short8v*)&zcur_[R3_ * 32 + ((grp ^ ((R3_ >> 1) & 3)) << 3)]; \
        }                                                                     \
        _Pragma("unroll")                                                     \
        for (int mt_ = 0; mt_ < 4; ++mt_)                                     \
            _Pragma("unroll")                                                 \
            for (int nt_ = 0; nt_ < 4; ++nt_)                                 \
                acc[mt_][nt_] = __builtin_amdgcn_mfma_f32_16x16x32_bf16(afc[mt_], bf_[nt_], acc[mt_][nt_], 0, 0, 0); \
    }                                                                         \
    asm volatile("s_waitcnt lgkmcnt(0)" ::: "memory");                        \
    __builtin_amdgcn_sched_barrier(0);                                        \
    __builtin_amdgcn_s_barrier();                                             \
} while (0)

    short8v afA[4], afB[4];
    #pragma unroll
    for (int mt = 0; mt < 4; ++mt) afA[mt] = *(const short8v*)(afbase + mt * 512);

    #pragma unroll 1
    for (int cib = 0; cib < 4; ++cib) {
        stage_xs(cib);
        asm volatile("s_waitcnt lgkmcnt(0)" ::: "memory");
        __builtin_amdgcn_sched_barrier(0);
        __builtin_amdgcn_s_barrier();

        zgen(cib * 6, (cib * 6) & 1);                   // prime Z for first chunk
        asm volatile("s_waitcnt lgkmcnt(0)" ::: "memory");
        __builtin_amdgcn_sched_barrier(0);
        __builtin_amdgcn_s_barrier();

        #pragma unroll 1
        for (int jj = 0; jj < 3; ++jj) {
            KSTEP(cib * 6 + jj * 2,     jj * 2,     afA, afB);
            KSTEP(cib * 6 + jj * 2 + 1, jj * 2 + 1, afB, afA);
        }
    }
#undef KSTEP

    // ---- epilogue: BN + relu + residual + relu + store ----
    #pragma unroll
    for (int mt = 0; mt < 4; ++mt) {
        #pragma unroll
        for (int nt = 0; nt < 4; ++nt) {
            int lw = nt * 16;                 // + lcol below
            int w = lw & 31;
            int l = l0 + (lw >> 5);
            int wl = w + lcol;
            if (wl < VV) {
                #pragma unroll
                for (int r = 0; r < 4; ++r) {
                    int c = wm * 64 + mt * 16 + grp * 4 + r;
                    float val = fmaf(acc[mt][nt][r], scsh[c], scsh[256 + c]);
                    val = fmaxf(val, 0.f);
                    size_t ad = ((size_t)(n * CC + c) * LL + l) * VV + wl;
                    val = fmaxf(val + x[ad], 0.f);
                    out[ad] = val;
                }
            }
        }
    }
}

// ===========================================================================
// Fallback path (ws too small): round-1/2 proven kernels (in-place on d_out)
// ===========================================================================
__global__ __launch_bounds__(256) void wsum_kernel(const float* __restrict__ x,
                                                   float* __restrict__ xs) {
    const int CHUNKS = 8;
    int t = blockIdx.x * 256 + threadIdx.x;
    if (t >= NB * CC * VV * CHUNKS) return;
    int v = t % VV;
    int r = t / VV;
    int chunk = r % CHUNKS;
    int nc = r / CHUNKS;
    int l0 = chunk * (LL / CHUNKS);
    const float* xp = x  + (size_t)nc * (LL * VV) + v;
    float*       op = xs + (size_t)nc * (LL * VV) + v;
    float ring[8];
    float run = 0.f;
    #pragma unroll
    for (int k = 0; k < 8; ++k) {
        int j = l0 - 8 + k;
        float val = (j >= 0) ? xp[j * VV] : 0.f;
        ring[k] = val; run += val;
    }
    for (int base = l0; base < l0 + LL / CHUNKS; base += 8) {
        #pragma unroll
        for (int k = 0; k < 8; ++k) {
            int l = base + k;
            float val = xp[l * VV];
            float o = run + val;
            op[l * VV] = o;
            run = o - ring[k];
            ring[k] = val;
        }
    }
}

__global__ __launch_bounds__(256) void fused_fallback_kernel(
    const float* xs, const float* __restrict__ x, const float* __restrict__ W,
    const float* __restrict__ A,
    const float* __restrict__ gamma, const float* __restrict__ beta,
    const float* __restrict__ mean, const float* __restrict__ var,
    float* out)
{
    __shared__ float xshf[CC][28];
    const int bid = blockIdx.x;
    const int n = bid >> 9;
    const int l = bid & 511;
    const int tid = threadIdx.x;
    const size_t nbase = (size_t)n * CC * LL * VV;
    for (int k = tid; k < CC * VV; k += 256) {
        int ci = k / VV, v = k - ci * VV;
        xshf[ci][v] = xs[nbase + (size_t)ci * (LL * VV) + (size_t)l * VV + v];
    }
    __syncthreads();
    const int c = tid;
    float Y[PP * VV];
    #pragma unroll
    for (int i = 0; i < PP * VV; ++i) Y[i] = 0.f;
    const float* Wpr = W + c * 256;
    #pragma unroll 1
    for (int ci = 0; ci < CC; ++ci) {
        float xv[VV];
        #pragma unroll
        for (int v = 0; v < VV; ++v) xv[v] = xshf[ci][v];
        float w0 = Wpr[ci], w1 = Wpr[65536 + ci], w2 = Wpr[131072 + ci];
        #pragma unroll
        for (int v = 0; v < VV; ++v) Y[v]          = fmaf(w0, xv[v], Y[v]);
        #pragma unroll
        for (int v = 0; v < VV; ++v) Y[VV + v]     = fmaf(w1, xv[v], Y[VV + v]);
        #pragma unroll
        for (int v = 0; v < VV; ++v) Y[2 * VV + v] = fmaf(w2, xv[v], Y[2 * VV + v]);
    }
    float o[VV];
    #pragma unroll
    for (int w = 0; w < VV; ++w) o[w] = 0.f;
    #pragma unroll
    for (int p = 0; p < PP; ++p)
        #pragma unroll
        for (int v = 0; v < VV; ++v) {
            float y = Y[p * VV + v];
            const float* Ap = A + (p * VV + v) * VV;
            #pragma unroll
            for (int w = 0; w < VV; ++w) o[w] = fmaf(y, Ap[w], o[w]);
        }
    float sc = gamma[c] * rsqrtf(var[c] + 1e-5f);
    float sh = beta[c] - mean[c] * sc;
    const float* resp = x   + nbase + (size_t)c * (LL * VV) + (size_t)l * VV;
    float*       outp = out + nbase + (size_t)c * (LL * VV) + (size_t)l * VV;
    #pragma unroll
    for (int w = 0; w < VV; ++w) {
        float t2 = fmaf(o[w], sc, sh);
        t2 = fmaxf(t2, 0.f);
        t2 = fmaxf(t2 + resp[w], 0.f);
        outp[w] = t2;
    }
}

extern "C" void kernel_launch(void* const* d_in, const int* in_sizes, int n_in,
                              void* d_out, int out_size, void* d_ws, size_t ws_size,
                              hipStream_t stream) {
    const float* x  = (const float*)d_in[0];
    const float* W  = (const float*)d_in[1];
    const float* A  = (const float*)d_in[2];
    const float* gm = (const float*)d_in[3];
    const float* bt = (const float*)d_in[4];
    const float* mn = (const float*)d_in[5];
    const float* vr = (const float*)d_in[6];
    float* out = (float*)d_out;

    if (ws_size >= (size_t)(OO * CC * sizeof(__hip_bfloat16))) {
        __hip_bfloat16* Wp = (__hip_bfloat16*)d_ws;
        wperm_kernel<<<dim3((OO * CC + 255) / 256), dim3(256), 0, stream>>>(W, Wp);
        fused_main_kernel<<<dim3(NB * (LL / LT)), dim3(256), 0, stream>>>(
            x, Wp, A, gm, bt, mn, vr, out);
    } else {
        const int threadsA = NB * CC * VV * 8;
        wsum_kernel<<<dim3((threadsA + 255) / 256), dim3(256), 0, stream>>>(x, out);
        fused_fallback_kernel<<<dim3(NB * LL), dim3(256), 0, stream>>>(
            out, x, W, A, gm, bt, mn, vr, out);
    }
}